// Round 7
// baseline (452.311 us; speedup 1.0000x reference)
//
#include <hip/hip_runtime.h>
#include <hip/hip_bf16.h>
#include <stdint.h>

// ---- problem constants (fixed shapes) ----
#define BTOT   256      // B*T frames
#define LX     197      // tokens incl CLS
#define CDIM   768
#define CADIM  384
#define TFR    8
#define LM1    196      // L-1
#define MTOT   50176    // BTOT*LM1

typedef unsigned short u16;
typedef short          bf16x8 __attribute__((ext_vector_type(8)));
typedef unsigned short u16x4  __attribute__((ext_vector_type(4)));
typedef unsigned short u16x8  __attribute__((ext_vector_type(8)));
typedef float          f32x4  __attribute__((ext_vector_type(4)));

typedef const __attribute__((address_space(1))) void gvoid_t;
typedef __attribute__((address_space(3))) void       svoid_t;

static __device__ __forceinline__ u16 f2bf(float f) {
  union { float f; uint32_t u; } v; v.f = f;
  uint32_t u = v.u;
  return (u16)((u + 0x7FFFu + ((u >> 16) & 1u)) >> 16);  // RNE
}
static __device__ __forceinline__ float bf2f(u16 h) {
  union { uint32_t u; float f; } v; v.u = ((uint32_t)h) << 16;
  return v.f;
}
// RNE f32->bf16 via intrinsic (compiler emits packed cvt where possible)
static __device__ __forceinline__ u16 f2bf_hw(float f) {
  union { __hip_bfloat16 b; u16 u; } v;
  v.b = __float2bfloat16(f);
  return v.u;
}

// ------- prep: weights bf16 + conv_w transpose + CLS-row copy -------
__global__ void prep_small(const float4* __restrict__ x4, float4* __restrict__ out4,
                           const float* __restrict__ W1, const float* __restrict__ W2,
                           const float* __restrict__ cw, u16* __restrict__ w1b,
                           u16* __restrict__ w2b, float* __restrict__ cwT) {
  int i = blockIdx.x * blockDim.x + threadIdx.x;
  if (i < CADIM * CDIM) { w1b[i] = f2bf(W1[i]); w2b[i] = f2bf(W2[i]); }
  if (i < CADIM * 27) {
    int a = i / 27; int tap = i - a * 27;
    cwT[tap * CADIM + a] = cw[i];        // [27][384] channel-contiguous
  }
  if (i < BTOT * 192) {                  // CLS rows: 256 frames x 192 float4
    int f = i / 192, v = i - f * 192;
    size_t off = (size_t)f * (LX * CDIM / 4) + v;
    out4[off] = x4[off];
  }
}

// ======================================================================
// LDS layout (both GEMMs, per buffer, per operand): super-row R (128 B)
// holds rows {2R, 2R+1} (32 bf16 each). Unswizzled slot u (0..7): u<4 ->
// row 2R chunk u; u>=4 -> row 2R+1 chunk u-4. Physical slot = u ^ (R&7).
// ds_read_b128 frag reads land 2 lanes/bank (free, m136); gload_lds
// destinations stay linear.
//
// Both GEMMs: BM=128 x BN=384, 768 thr / 12 waves (2M x 6N, per-wave
// 64x64 = 4x4 fragments), BK=32, 2-phase dbuf + __syncthreads (the only
// structure that never regressed this session). Wide BN minimizes
// staged bytes (session model: dur ~ staged_bytes / 4-6 TB/s):
//   fc1: A(x fp32) staged once: 385 MB total (R6-measured 98.4 us)
//   fc2: 301 MB total (was 451 at BN=128)
// fc1: waves 0-3 reg-stage A from fp32 x (cvt in-register); waves 4-11
// stage B via gload_lds. fc2: waves 0-3 stage A (h2, bf16) via
// gload_lds; waves 4-11 stage B. LDS 16+48 = 64 KB -> 2 blocks/CU.
// ======================================================================

// ---------------- fc1: h1[m, a] = x[m,:] . W1[a,:] + b1[a] ----------------
// BM=128, BN=384 (full N), 768 threads. A = x fp32 (CLS-skip), in-register
// cvt by waves 0-3; B = w1b staged by waves 4-11 via global_load_lds.
__global__ __launch_bounds__(768, 2) void fc1_gemm(
    const float* __restrict__ X,  // x fp32 [BTOT][LX][CDIM]
    const u16* __restrict__ Bw,   // w1b [384][768] bf16 (N x K row-major)
    const float* __restrict__ bias,
    u16* __restrict__ Hout)       // [50176][384] bf16
{
  __shared__ __align__(16) u16 As[2 * 128 * 32];   // 16 KB
  __shared__ __align__(16) u16 Bs[2 * 384 * 32];   // 48 KB
  const int tid  = threadIdx.x;
  const int lane = tid & 63;
  const int wave = tid >> 6;           // 0..11
  const int m0 = blockIdx.x * 128;
  const int lm = lane & 15;
  const int lk = lane >> 4;
  const int wr = wave / 6;             // 0..1  (M half)
  const int wc = wave - wr * 6;        // 0..5  (N sixth)
  const int wm = wr * 64;
  const int wn = wc * 64;
  const bool is_a = (wave < 4);

  // ---- A reg-staging (waves 0-3): thread t: rows g+32s (g=t>>3), float4 q
  const int g = tid >> 3;              // 0..31 when is_a
  const int q = tid & 7;
  size_t arow[4];
  int awst[4];
  if (is_a) {
#pragma unroll
    for (int s = 0; s < 4; ++s) {
      int row = g + 32 * s;
      int tok = m0 + row;
      int bt = tok / LM1;
      int l  = tok - bt * LM1;
      arow[s] = (size_t)(bt * LX + 1 + l) * CDIM + q * 4;   // fp32, skip CLS
      int R    = row >> 1;
      int uu   = (row & 1) * 4 + (q >> 1);
      int slot = uu ^ (R & 7);
      awst[s]  = R * 64 + slot * 8 + (q & 1) * 4;           // u16 elems
    }
  }

  // ---- B staging (waves 4-11): 8 waves x 3 instrs cover 384 rows.
  const int wb  = wave - 4;            // 0..7 when !is_a
  const int u   = (lane & 7) ^ (lane >> 3);
  const int rr  = 2 * (lane >> 3) + (u >> 2);
  const int cko = (u & 3) * 8;
  size_t boff[3];
  int ldst[3];
  if (!is_a) {
#pragma unroll
    for (int s = 0; s < 3; ++s) {
      int row = wb * 48 + s * 16 + rr;
      boff[s] = (size_t)row * CDIM + cko;
      ldst[s] = (wb * 24 + s * 8) * 64;                     // u16 elems
    }
  }

  // fragment read addressing (swizzled)
  const int lmh   = lm >> 1;
  const int slotp = (((lm & 1) << 2) | lk) ^ lmh;
  const int abase = ((wm >> 1) + lmh) * 64 + slotp * 8;
  const int bbase = ((wn >> 1) + lmh) * 64 + slotp * 8;

  f32x4 acc[4][4];
#pragma unroll
  for (int i = 0; i < 4; i++)
#pragma unroll
    for (int j = 0; j < 4; j++) acc[i][j] = (f32x4)0.0f;

  float4 areg[4];

  // ---- prologue: tile 0 ----
  if (is_a) {
#pragma unroll
    for (int s = 0; s < 4; ++s) areg[s] = *(const float4*)(X + arow[s]);
#pragma unroll
    for (int s = 0; s < 4; ++s) {
      u16x4 o;
      o[0] = f2bf_hw(areg[s].x); o[1] = f2bf_hw(areg[s].y);
      o[2] = f2bf_hw(areg[s].z); o[3] = f2bf_hw(areg[s].w);
      *(u16x4*)&As[awst[s]] = o;
    }
  } else {
#pragma unroll
    for (int s = 0; s < 3; ++s)
      __builtin_amdgcn_global_load_lds((gvoid_t*)(Bw + boff[s]),
          (svoid_t*)(Bs + ldst[s]), 16, 0, 0);
  }
  __syncthreads();

  // ---- K = 768 -> 24 steps of 32, 2-phase double-buffered ----
  int cur = 0;
  for (int kt = 0; kt < 23; ++kt) {
    const int k1 = (kt + 1) * 32;
    const int nb = cur ^ 1;
    if (is_a) {
#pragma unroll
      for (int s = 0; s < 4; ++s) areg[s] = *(const float4*)(X + arow[s] + k1);
    } else {
#pragma unroll
      for (int s = 0; s < 3; ++s)
        __builtin_amdgcn_global_load_lds((gvoid_t*)(Bw + boff[s] + k1),
            (svoid_t*)(Bs + nb * 12288 + ldst[s]), 16, 0, 0);
    }
    {
      const u16* Ab = As + cur * 4096;
      const u16* Bb = Bs + cur * 12288;
      bf16x8 af[4], bfr[4];
#pragma unroll
      for (int i = 0; i < 4; i++) af[i] = *(const bf16x8*)&Ab[abase + i * 512];
#pragma unroll
      for (int j = 0; j < 4; j++) bfr[j] = *(const bf16x8*)&Bb[bbase + j * 512];
#pragma unroll
      for (int i = 0; i < 4; i++)
#pragma unroll
        for (int j = 0; j < 4; j++)
          acc[i][j] = __builtin_amdgcn_mfma_f32_16x16x32_bf16(af[i], bfr[j], acc[i][j], 0, 0, 0);
    }
    if (is_a) {
#pragma unroll
      for (int s = 0; s < 4; ++s) {
        u16x4 o;
        o[0] = f2bf_hw(areg[s].x); o[1] = f2bf_hw(areg[s].y);
        o[2] = f2bf_hw(areg[s].z); o[3] = f2bf_hw(areg[s].w);
        *(u16x4*)&As[nb * 4096 + awst[s]] = o;
      }
    }
    __syncthreads();
    cur ^= 1;
  }
  {
    const u16* Ab = As + cur * 4096;
    const u16* Bb = Bs + cur * 12288;
    bf16x8 af[4], bfr[4];
#pragma unroll
    for (int i = 0; i < 4; i++) af[i] = *(const bf16x8*)&Ab[abase + i * 512];
#pragma unroll
    for (int j = 0; j < 4; j++) bfr[j] = *(const bf16x8*)&Bb[bbase + j * 512];
#pragma unroll
    for (int i = 0; i < 4; i++)
#pragma unroll
      for (int j = 0; j < 4; j++)
        acc[i][j] = __builtin_amdgcn_mfma_f32_16x16x32_bf16(af[i], bfr[j], acc[i][j], 0, 0, 0);
  }

#pragma unroll
  for (int i = 0; i < 4; i++) {
    int rbase = m0 + wm + i * 16 + lk * 4;
#pragma unroll
    for (int j = 0; j < 4; j++) {
      int col = wn + j * 16 + lm;
      float bv = bias[col];
#pragma unroll
      for (int r = 0; r < 4; r++)
        Hout[(rbase + r) * CADIM + col] = f2bf(acc[i][j][r] + bv);
    }
  }
}

// ---------------- depthwise 3x3x3 conv: LDS-tiled ----------------
// Block = (frame f, 32-ch chunk). Stage 3 frames x 196 pos x 32 ch into
// LDS (37.6 KB) ONCE -> global h1 reads drop 12x -> 3x (115 MB total).
// Thread: cg = tid&3 (16B chunk), pidx = tid>>2; computes up to 4
// positions x 8 ch from LDS. Per-tap weight reload keeps VGPR ~100.
__global__ __launch_bounds__(256) void dwconv(
    const u16* __restrict__ h1, const float* __restrict__ cwT,
    const float* __restrict__ cb, u16* __restrict__ h2)
{
  __shared__ __align__(16) u16 lin[3 * 196 * 32];   // 37,632 B
  const int tid = threadIdx.x;
  const int f   = blockIdx.x;          // frame 0..255
  const int cc  = blockIdx.y;          // 0..11, channels cc*32..+31
  const int tv  = f & 7;               // t within video

  // ---- stage: 2352 16B-chunks; zero-fill temporally-invalid frames ----
  for (int i = tid; i < 3 * 196 * 4; i += 256) {
    int fd  = i / 784;                 // 0..2 (= dt+1)
    int rem = i - fd * 784;            // pos*4 + c8
    int pos = rem >> 2;
    int c8  = rem & 3;
    int tt  = tv + fd - 1;
    u16x8 v = (u16x8)0;
    if (tt >= 0 && tt < TFR) {
      const u16* src = h1 + ((size_t)(f + fd - 1) * LM1 + pos) * CADIM
                          + cc * 32 + c8 * 8;
      v = *(const u16x8*)src;
    }
    *(u16x8*)&lin[(fd * 196 + pos) * 32 + c8 * 8] = v;
  }
  __syncthreads();

  const int cg    = tid & 3;           // 8-ch group within the 32
  const int pidx  = tid >> 2;          // 0..63
  const int cbase = cc * 32 + cg * 8;

  float bv[8];
#pragma unroll
  for (int c = 0; c < 8; ++c) bv[c] = cb[cbase + c];

  float acc[4][8];
  int hk[4], wk[4];
#pragma unroll
  for (int k = 0; k < 4; ++k) {
    int p = pidx + 64 * k;
    hk[k] = p / 14;
    wk[k] = p - hk[k] * 14;
#pragma unroll
    for (int c = 0; c < 8; ++c) acc[k][c] = bv[c];
  }

  for (int dt = 0; dt < 3; ++dt) {
#pragma unroll
    for (int j = 0; j < 9; ++j) {
      const int dh = j / 3 - 1, dw = j % 3 - 1;
      float w8[8];
      const float* wp8 = cwT + (dt * 9 + j) * CADIM + cbase;
#pragma unroll
      for (int c = 0; c < 8; ++c) w8[c] = wp8[c];
#pragma unroll
      for (int k = 0; k < 4; ++k) {
        int p = pidx + 64 * k;
        if (p >= 196) continue;
        int hh = hk[k] + dh, ww = wk[k] + dw;
        if (hh < 0 || hh >= 14 || ww < 0 || ww >= 14) continue;
        const u16x8 v = *(const u16x8*)&lin[(dt * 196 + hh * 14 + ww) * 32 + cg * 8];
#pragma unroll
        for (int c = 0; c < 8; ++c)
          acc[k][c] += bf2f((u16)v[c]) * w8[c];
      }
    }
  }

#pragma unroll
  for (int k = 0; k < 4; ++k) {
    int p = pidx + 64 * k;
    if (p < 196) {
      u16x8 o;
#pragma unroll
      for (int c = 0; c < 8; ++c) o[c] = f2bf(acc[k][c]);
      *(u16x8*)(h2 + ((size_t)f * LM1 + p) * CADIM + cbase) = o;
    }
  }
}

// ---------------- fc2 + residual: out = x + h2 . W2^T + b2 ----------------
// BM=128, BN=384 (half N), 768 threads / 12 waves. Waves 0-3 stage A
// (h2 bf16, gload_lds), waves 4-11 stage B. Epilogue R1-exact.
__global__ __launch_bounds__(768, 2) void fc2_gemm(
    const u16* __restrict__ A,    // h2 [50176][384] bf16
    const u16* __restrict__ Bw,   // w2b [768][384] bf16 (N x K row-major)
    const float* __restrict__ bias,
    const float* __restrict__ x,
    float* __restrict__ out)
{
  __shared__ __align__(16) u16 As[2 * 128 * 32];   // 16 KB
  __shared__ __align__(16) u16 Bs[2 * 384 * 32];   // 48 KB
  const int tid  = threadIdx.x;
  const int lane = tid & 63;
  const int wave = tid >> 6;           // 0..11
  const int m0 = blockIdx.x * 128;
  const int n0 = blockIdx.y * 384;
  const int lm = lane & 15;
  const int lk = lane >> 4;
  const int wr = wave / 6;             // 0..1
  const int wc = wave - wr * 6;        // 0..5
  const int wm = wr * 64;
  const int wn = wc * 64;
  const bool is_a = (wave < 4);

  const int u   = (lane & 7) ^ (lane >> 3);
  const int rr  = 2 * (lane >> 3) + (u >> 2);
  const int cko = (u & 3) * 8;

  // A staging (waves 0-3): 2 instrs x 16 rows cover rows wave*32..+31
  size_t aoff[2];
  int lasta[2];
  if (is_a) {
#pragma unroll
    for (int s = 0; s < 2; ++s) {
      int row = wave * 32 + s * 16 + rr;
      aoff[s]  = (size_t)(m0 + row) * CADIM + cko;
      lasta[s] = (wave * 16 + s * 8) * 64;
    }
  }
  // B staging (waves 4-11): 3 instrs x 16 rows cover 384 rows
  const int wb = wave - 4;
  size_t boff[3];
  int ldst[3];
  if (!is_a) {
#pragma unroll
    for (int s = 0; s < 3; ++s) {
      int row = wb * 48 + s * 16 + rr;
      boff[s] = (size_t)(n0 + row) * CADIM + cko;
      ldst[s] = (wb * 24 + s * 8) * 64;
    }
  }

  const int lmh   = lm >> 1;
  const int slotp = (((lm & 1) << 2) | lk) ^ lmh;
  const int abase = ((wm >> 1) + lmh) * 64 + slotp * 8;
  const int bbase = ((wn >> 1) + lmh) * 64 + slotp * 8;

  f32x4 acc[4][4];
#pragma unroll
  for (int i = 0; i < 4; i++)
#pragma unroll
    for (int j = 0; j < 4; j++) acc[i][j] = (f32x4)0.0f;

  // prologue: tile 0
  if (is_a) {
#pragma unroll
    for (int s = 0; s < 2; ++s)
      __builtin_amdgcn_global_load_lds((gvoid_t*)(A + aoff[s]),
          (svoid_t*)(As + lasta[s]), 16, 0, 0);
  } else {
#pragma unroll
    for (int s = 0; s < 3; ++s)
      __builtin_amdgcn_global_load_lds((gvoid_t*)(Bw + boff[s]),
          (svoid_t*)(Bs + ldst[s]), 16, 0, 0);
  }
  __syncthreads();

  // K = 384 -> 12 steps of 32, 2-phase double-buffered
  int cur = 0;
  for (int kt = 0; kt < 11; ++kt) {
    const int k1 = (kt + 1) * 32;
    const int nb = cur ^ 1;
    if (is_a) {
#pragma unroll
      for (int s = 0; s < 2; ++s)
        __builtin_amdgcn_global_load_lds((gvoid_t*)(A + aoff[s] + k1),
            (svoid_t*)(As + nb * 4096 + lasta[s]), 16, 0, 0);
    } else {
#pragma unroll
      for (int s = 0; s < 3; ++s)
        __builtin_amdgcn_global_load_lds((gvoid_t*)(Bw + boff[s] + k1),
            (svoid_t*)(Bs + nb * 12288 + ldst[s]), 16, 0, 0);
    }
    {
      const u16* Ab = As + cur * 4096;
      const u16* Bb = Bs + cur * 12288;
      bf16x8 af[4], bfr[4];
#pragma unroll
      for (int i = 0; i < 4; i++) af[i] = *(const bf16x8*)&Ab[abase + i * 512];
#pragma unroll
      for (int j = 0; j < 4; j++) bfr[j] = *(const bf16x8*)&Bb[bbase + j * 512];
#pragma unroll
      for (int i = 0; i < 4; i++)
#pragma unroll
        for (int j = 0; j < 4; j++)
          acc[i][j] = __builtin_amdgcn_mfma_f32_16x16x32_bf16(af[i], bfr[j], acc[i][j], 0, 0, 0);
    }
    __syncthreads();
    cur ^= 1;
  }
  {
    const u16* Ab = As + cur * 4096;
    const u16* Bb = Bs + cur * 12288;
    bf16x8 af[4], bfr[4];
#pragma unroll
    for (int i = 0; i < 4; i++) af[i] = *(const bf16x8*)&Ab[abase + i * 512];
#pragma unroll
    for (int j = 0; j < 4; j++) bfr[j] = *(const bf16x8*)&Bb[bbase + j * 512];
#pragma unroll
    for (int i = 0; i < 4; i++)
#pragma unroll
      for (int j = 0; j < 4; j++)
        acc[i][j] = __builtin_amdgcn_mfma_f32_16x16x32_bf16(af[i], bfr[j], acc[i][j], 0, 0, 0);
  }

  // epilogue (R1-exact): residual add + bias, fp32 out
  float bve[4];
#pragma unroll
  for (int j = 0; j < 4; j++) bve[j] = bias[n0 + wn + j * 16 + lm];
#pragma unroll
  for (int i = 0; i < 4; i++) {
    int rbase = m0 + wm + i * 16 + lk * 4;
    size_t orow[4];
#pragma unroll
    for (int r = 0; r < 4; r++) {
      int tok = rbase + r;
      int bt = tok / LM1;
      int l  = tok - bt * LM1;
      orow[r] = (size_t)(bt * LX + 1 + l) * CDIM + (n0 + wn + lm);
    }
    float xv[4][4];
#pragma unroll
    for (int r = 0; r < 4; r++)
#pragma unroll
      for (int j = 0; j < 4; j++)
        xv[r][j] = x[orow[r] + j * 16];
#pragma unroll
    for (int r = 0; r < 4; r++)
#pragma unroll
      for (int j = 0; j < 4; j++)
        out[orow[r] + j * 16] = xv[r][j] + acc[i][j][r] + bve[j];
  }
}

// ---------------- launch ----------------
extern "C" void kernel_launch(void* const* d_in, const int* in_sizes, int n_in,
                              void* d_out, int out_size, void* d_ws, size_t ws_size,
                              hipStream_t stream) {
  const float* x  = (const float*)d_in[0];
  const float* W1 = (const float*)d_in[1];
  const float* b1 = (const float*)d_in[2];
  const float* cw = (const float*)d_in[3];
  const float* cb = (const float*)d_in[4];
  const float* W2 = (const float*)d_in[5];
  const float* b2 = (const float*)d_in[6];
  float* out = (float*)d_out;

  // workspace: 78.3 MB total
  char* ws = (char*)d_ws;
  u16*   w1b = (u16*)(ws + 0);              //    589,824 B
  u16*   w2b = (u16*)(ws + 589824);         //    589,824 B
  float* cwT = (float*)(ws + 1179648);      //     41,472 B
  u16*   h1  = (u16*)(ws + 1245184);        // 38,535,168 B
  u16*   h2  = (u16*)(ws + 39780352);       // 38,535,168 B  (end 78,315,520)

  prep_small<<<1152, 256, 0, stream>>>((const float4*)x, (float4*)out,
                                       W1, W2, cw, w1b, w2b, cwT);
  fc1_gemm<<<MTOT / 128, 768, 0, stream>>>(x, w1b, b1, h1);
  dwconv  <<<dim3(BTOT, 12), 256, 0, stream>>>(h1, cwT, cb, h2);
  fc2_gemm<<<dim3(MTOT / 128, 2), 768, 0, stream>>>(h2, w2b, b2, x, out);
}

// Round 8
// 434.169 us; speedup vs baseline: 1.0418x; 1.0418x over previous
//
#include <hip/hip_runtime.h>
#include <hip/hip_bf16.h>
#include <stdint.h>

// ---- problem constants (fixed shapes) ----
#define BTOT   256      // B*T frames
#define LX     197      // tokens incl CLS
#define CDIM   768
#define CADIM  384
#define TFR    8
#define LM1    196      // L-1
#define MTOT   50176    // BTOT*LM1

typedef unsigned short u16;
typedef short          bf16x8 __attribute__((ext_vector_type(8)));
typedef unsigned short u16x4  __attribute__((ext_vector_type(4)));
typedef unsigned short u16x8  __attribute__((ext_vector_type(8)));
typedef float          f32x4  __attribute__((ext_vector_type(4)));

typedef const __attribute__((address_space(1))) void gvoid_t;
typedef __attribute__((address_space(3))) void       svoid_t;

static __device__ __forceinline__ u16 f2bf(float f) {
  union { float f; uint32_t u; } v; v.f = f;
  uint32_t u = v.u;
  return (u16)((u + 0x7FFFu + ((u >> 16) & 1u)) >> 16);  // RNE
}
static __device__ __forceinline__ float bf2f(u16 h) {
  union { uint32_t u; float f; } v; v.u = ((uint32_t)h) << 16;
  return v.f;
}
// RNE f32->bf16 via intrinsic (compiler emits packed cvt where possible)
static __device__ __forceinline__ u16 f2bf_hw(float f) {
  union { __hip_bfloat16 b; u16 u; } v;
  v.b = __float2bfloat16(f);
  return v.u;
}

// ------- prep: weights bf16 + conv_w transpose + CLS-row copy -------
__global__ void prep_small(const float4* __restrict__ x4, float4* __restrict__ out4,
                           const float* __restrict__ W1, const float* __restrict__ W2,
                           const float* __restrict__ cw, u16* __restrict__ w1b,
                           u16* __restrict__ w2b, float* __restrict__ cwT) {
  int i = blockIdx.x * blockDim.x + threadIdx.x;
  if (i < CADIM * CDIM) { w1b[i] = f2bf(W1[i]); w2b[i] = f2bf(W2[i]); }
  if (i < CADIM * 27) {
    int a = i / 27; int tap = i - a * 27;
    cwT[tap * CADIM + a] = cw[i];        // [27][384] channel-contiguous
  }
  if (i < BTOT * 192) {                  // CLS rows: 256 frames x 192 float4
    int f = i / 192, v = i - f * 192;
    size_t off = (size_t)f * (LX * CDIM / 4) + v;
    out4[off] = x4[off];
  }
}

// ======================================================================
// LDS layout (both GEMMs, per buffer, per operand): super-row R (128 B)
// holds rows {2R, 2R+1} (32 bf16 each). Unswizzled slot u (0..7): u<4 ->
// row 2R chunk u; u>=4 -> row 2R+1 chunk u-4. Physical slot = u ^ (R&7).
// ds_read_b128 frag reads land 2 lanes/bank (free, m136); gload_lds
// destinations stay linear.
//
// fc1: BM=128 x BN=384 (full N) -> x staged exactly once (R6-measured
// 98.4 us). 768 thr / 12 waves; waves 0-3 reg-stage A from fp32 x,
// waves 4-11 stage B via gload_lds. LDS 64 KB.
//
// fc2 (this round): back to the 2352-block BM=128 x BN=128 shape (best
// measured 94.8; wide-BN cut bytes but killed overlap, R7 +12us) + T1
// XCD-aware bijective swizzle: logical tiles ordered A-stripe-major and
// chunked per XCD, so the 6 N-tiles sharing an A-stripe run on ONE
// XCD back-to-back -> 5/6 of A staging becomes XCD-L2 hits (~200cy)
// instead of L3/HBM (~450-900cy). 2352 = 8*294 exactly -> simple
// bijective form valid (ERRATA #11).
// ======================================================================

// ---------------- fc1: h1[m, a] = x[m,:] . W1[a,:] + b1[a] ----------------
__global__ __launch_bounds__(768, 2) void fc1_gemm(
    const float* __restrict__ X,  // x fp32 [BTOT][LX][CDIM]
    const u16* __restrict__ Bw,   // w1b [384][768] bf16 (N x K row-major)
    const float* __restrict__ bias,
    u16* __restrict__ Hout)       // [50176][384] bf16
{
  __shared__ __align__(16) u16 As[2 * 128 * 32];   // 16 KB
  __shared__ __align__(16) u16 Bs[2 * 384 * 32];   // 48 KB
  const int tid  = threadIdx.x;
  const int lane = tid & 63;
  const int wave = tid >> 6;           // 0..11
  const int m0 = blockIdx.x * 128;
  const int lm = lane & 15;
  const int lk = lane >> 4;
  const int wr = wave / 6;             // 0..1  (M half)
  const int wc = wave - wr * 6;        // 0..5  (N sixth)
  const int wm = wr * 64;
  const int wn = wc * 64;
  const bool is_a = (wave < 4);

  // ---- A reg-staging (waves 0-3): thread t: rows g+32s (g=t>>3), float4 q
  const int g = tid >> 3;              // 0..31 when is_a
  const int q = tid & 7;
  size_t arow[4];
  int awst[4];
  if (is_a) {
#pragma unroll
    for (int s = 0; s < 4; ++s) {
      int row = g + 32 * s;
      int tok = m0 + row;
      int bt = tok / LM1;
      int l  = tok - bt * LM1;
      arow[s] = (size_t)(bt * LX + 1 + l) * CDIM + q * 4;   // fp32, skip CLS
      int R    = row >> 1;
      int uu   = (row & 1) * 4 + (q >> 1);
      int slot = uu ^ (R & 7);
      awst[s]  = R * 64 + slot * 8 + (q & 1) * 4;           // u16 elems
    }
  }

  // ---- B staging (waves 4-11): 8 waves x 3 instrs cover 384 rows.
  const int wb  = wave - 4;            // 0..7 when !is_a
  const int u   = (lane & 7) ^ (lane >> 3);
  const int rr  = 2 * (lane >> 3) + (u >> 2);
  const int cko = (u & 3) * 8;
  size_t boff[3];
  int ldst[3];
  if (!is_a) {
#pragma unroll
    for (int s = 0; s < 3; ++s) {
      int row = wb * 48 + s * 16 + rr;
      boff[s] = (size_t)row * CDIM + cko;
      ldst[s] = (wb * 24 + s * 8) * 64;                     // u16 elems
    }
  }

  // fragment read addressing (swizzled)
  const int lmh   = lm >> 1;
  const int slotp = (((lm & 1) << 2) | lk) ^ lmh;
  const int abase = ((wm >> 1) + lmh) * 64 + slotp * 8;
  const int bbase = ((wn >> 1) + lmh) * 64 + slotp * 8;

  f32x4 acc[4][4];
#pragma unroll
  for (int i = 0; i < 4; i++)
#pragma unroll
    for (int j = 0; j < 4; j++) acc[i][j] = (f32x4)0.0f;

  float4 areg[4];

  // ---- prologue: tile 0 ----
  if (is_a) {
#pragma unroll
    for (int s = 0; s < 4; ++s) areg[s] = *(const float4*)(X + arow[s]);
#pragma unroll
    for (int s = 0; s < 4; ++s) {
      u16x4 o;
      o[0] = f2bf_hw(areg[s].x); o[1] = f2bf_hw(areg[s].y);
      o[2] = f2bf_hw(areg[s].z); o[3] = f2bf_hw(areg[s].w);
      *(u16x4*)&As[awst[s]] = o;
    }
  } else {
#pragma unroll
    for (int s = 0; s < 3; ++s)
      __builtin_amdgcn_global_load_lds((gvoid_t*)(Bw + boff[s]),
          (svoid_t*)(Bs + ldst[s]), 16, 0, 0);
  }
  __syncthreads();

  // ---- K = 768 -> 24 steps of 32, 2-phase double-buffered ----
  int cur = 0;
  for (int kt = 0; kt < 23; ++kt) {
    const int k1 = (kt + 1) * 32;
    const int nb = cur ^ 1;
    if (is_a) {
#pragma unroll
      for (int s = 0; s < 4; ++s) areg[s] = *(const float4*)(X + arow[s] + k1);
    } else {
#pragma unroll
      for (int s = 0; s < 3; ++s)
        __builtin_amdgcn_global_load_lds((gvoid_t*)(Bw + boff[s] + k1),
            (svoid_t*)(Bs + nb * 12288 + ldst[s]), 16, 0, 0);
    }
    {
      const u16* Ab = As + cur * 4096;
      const u16* Bb = Bs + cur * 12288;
      bf16x8 af[4], bfr[4];
#pragma unroll
      for (int i = 0; i < 4; i++) af[i] = *(const bf16x8*)&Ab[abase + i * 512];
#pragma unroll
      for (int j = 0; j < 4; j++) bfr[j] = *(const bf16x8*)&Bb[bbase + j * 512];
#pragma unroll
      for (int i = 0; i < 4; i++)
#pragma unroll
        for (int j = 0; j < 4; j++)
          acc[i][j] = __builtin_amdgcn_mfma_f32_16x16x32_bf16(af[i], bfr[j], acc[i][j], 0, 0, 0);
    }
    if (is_a) {
#pragma unroll
      for (int s = 0; s < 4; ++s) {
        u16x4 o;
        o[0] = f2bf_hw(areg[s].x); o[1] = f2bf_hw(areg[s].y);
        o[2] = f2bf_hw(areg[s].z); o[3] = f2bf_hw(areg[s].w);
        *(u16x4*)&As[nb * 4096 + awst[s]] = o;
      }
    }
    __syncthreads();
    cur ^= 1;
  }
  {
    const u16* Ab = As + cur * 4096;
    const u16* Bb = Bs + cur * 12288;
    bf16x8 af[4], bfr[4];
#pragma unroll
    for (int i = 0; i < 4; i++) af[i] = *(const bf16x8*)&Ab[abase + i * 512];
#pragma unroll
    for (int j = 0; j < 4; j++) bfr[j] = *(const bf16x8*)&Bb[bbase + j * 512];
#pragma unroll
    for (int i = 0; i < 4; i++)
#pragma unroll
      for (int j = 0; j < 4; j++)
        acc[i][j] = __builtin_amdgcn_mfma_f32_16x16x32_bf16(af[i], bfr[j], acc[i][j], 0, 0, 0);
  }

#pragma unroll
  for (int i = 0; i < 4; i++) {
    int rbase = m0 + wm + i * 16 + lk * 4;
#pragma unroll
    for (int j = 0; j < 4; j++) {
      int col = wn + j * 16 + lm;
      float bv = bias[col];
#pragma unroll
      for (int r = 0; r < 4; r++)
        Hout[(rbase + r) * CADIM + col] = f2bf(acc[i][j][r] + bv);
    }
  }
}

// ---------------- depthwise 3x3x3 conv: LDS-tiled ----------------
__global__ __launch_bounds__(256) void dwconv(
    const u16* __restrict__ h1, const float* __restrict__ cwT,
    const float* __restrict__ cb, u16* __restrict__ h2)
{
  __shared__ __align__(16) u16 lin[3 * 196 * 32];   // 37,632 B
  const int tid = threadIdx.x;
  const int f   = blockIdx.x;          // frame 0..255
  const int cc  = blockIdx.y;          // 0..11, channels cc*32..+31
  const int tv  = f & 7;               // t within video

  // ---- stage: 2352 16B-chunks; zero-fill temporally-invalid frames ----
  for (int i = tid; i < 3 * 196 * 4; i += 256) {
    int fd  = i / 784;                 // 0..2 (= dt+1)
    int rem = i - fd * 784;            // pos*4 + c8
    int pos = rem >> 2;
    int c8  = rem & 3;
    int tt  = tv + fd - 1;
    u16x8 v = (u16x8)0;
    if (tt >= 0 && tt < TFR) {
      const u16* src = h1 + ((size_t)(f + fd - 1) * LM1 + pos) * CADIM
                          + cc * 32 + c8 * 8;
      v = *(const u16x8*)src;
    }
    *(u16x8*)&lin[(fd * 196 + pos) * 32 + c8 * 8] = v;
  }
  __syncthreads();

  const int cg    = tid & 3;           // 8-ch group within the 32
  const int pidx  = tid >> 2;          // 0..63
  const int cbase = cc * 32 + cg * 8;

  float bv[8];
#pragma unroll
  for (int c = 0; c < 8; ++c) bv[c] = cb[cbase + c];

  float acc[4][8];
  int hk[4], wk[4];
#pragma unroll
  for (int k = 0; k < 4; ++k) {
    int p = pidx + 64 * k;
    hk[k] = p / 14;
    wk[k] = p - hk[k] * 14;
#pragma unroll
    for (int c = 0; c < 8; ++c) acc[k][c] = bv[c];
  }

  for (int dt = 0; dt < 3; ++dt) {
#pragma unroll
    for (int j = 0; j < 9; ++j) {
      const int dh = j / 3 - 1, dw = j % 3 - 1;
      float w8[8];
      const float* wp8 = cwT + (dt * 9 + j) * CADIM + cbase;
#pragma unroll
      for (int c = 0; c < 8; ++c) w8[c] = wp8[c];
#pragma unroll
      for (int k = 0; k < 4; ++k) {
        int p = pidx + 64 * k;
        if (p >= 196) continue;
        int hh = hk[k] + dh, ww = wk[k] + dw;
        if (hh < 0 || hh >= 14 || ww < 0 || ww >= 14) continue;
        const u16x8 v = *(const u16x8*)&lin[(dt * 196 + hh * 14 + ww) * 32 + cg * 8];
#pragma unroll
        for (int c = 0; c < 8; ++c)
          acc[k][c] += bf2f((u16)v[c]) * w8[c];
      }
    }
  }

#pragma unroll
  for (int k = 0; k < 4; ++k) {
    int p = pidx + 64 * k;
    if (p < 196) {
      u16x8 o;
#pragma unroll
      for (int c = 0; c < 8; ++c) o[c] = f2bf(acc[k][c]);
      *(u16x8*)(h2 + ((size_t)f * LM1 + p) * CADIM + cbase) = o;
    }
  }
}

// ---------------- fc2 + residual: out = x + h2 . W2^T + b2 ----------------
// R1-exact structure (best measured) + T1 XCD-aware bijective swizzle:
// logical tiles A-stripe-major, chunked per XCD (2352 = 8*294 exactly).
__global__ __launch_bounds__(256) void fc2_gemm(
    const u16* __restrict__ A,    // h2 [50176][384] bf16
    const u16* __restrict__ Bw,   // w2b [768][384] bf16 (N x K row-major)
    const float* __restrict__ bias,
    const float* __restrict__ x,
    float* __restrict__ out)
{
  __shared__ __align__(16) u16 As[2 * 128 * 32];
  __shared__ __align__(16) u16 Bs[2 * 128 * 32];
  const int tid  = threadIdx.x;
  const int lane = tid & 63;
  const int wave = tid >> 6;

  // T1 XCD swizzle: orig -> (xcd, idx) -> logical, A-stripe-major.
  // HW round-robins launched id across the 8 XCDs; logical range
  // [xcd*294, (xcd+1)*294) executes on XCD xcd, and the 6 N-tiles of an
  // A-stripe are consecutive logicals -> same XCD -> A-panel L2-resident.
  const int orig = blockIdx.x;          // 0..2351
  const int lgc  = (orig & 7) * 294 + (orig >> 3);
  const int lmt  = lgc / 6;             // A-stripe (m-tile) 0..391
  const int lnt  = lgc - lmt * 6;       // n-tile 0..5
  const int m0 = lmt * 128;
  const int n0 = lnt * 128;

  const int lm = lane & 15;
  const int lk = lane >> 4;
  const int wm = (wave & 1) * 64;
  const int wn = (wave >> 1) * 64;

  const int u   = (lane & 7) ^ (lane >> 3);
  const int rr  = 2 * (lane >> 3) + (u >> 2);
  const int cko = (u & 3) * 8;
  size_t aoff[2], boff[2];
  int ldst[2];
#pragma unroll
  for (int s = 0; s < 2; ++s) {
    int row = wave * 32 + s * 16 + rr;
    aoff[s] = (size_t)(m0 + row) * CADIM + cko;
    boff[s] = (size_t)(n0 + row) * CADIM + cko;
    ldst[s] = (wave * 16 + s * 8) * 64;
  }

  const int lmh   = lm >> 1;
  const int slotp = (((lm & 1) << 2) | lk) ^ lmh;
  const int abase = ((wm >> 1) + lmh) * 64 + slotp * 8;
  const int bbase = ((wn >> 1) + lmh) * 64 + slotp * 8;

  f32x4 acc[4][4];
#pragma unroll
  for (int i = 0; i < 4; i++)
#pragma unroll
    for (int j = 0; j < 4; j++) acc[i][j] = (f32x4)0.0f;

  // K = 384 -> 12 steps of 32, double-buffered (R1-exact)
#pragma unroll
  for (int s = 0; s < 2; ++s) {
    __builtin_amdgcn_global_load_lds((gvoid_t*)(A + aoff[s]),
        (svoid_t*)(As + ldst[s]), 16, 0, 0);
    __builtin_amdgcn_global_load_lds((gvoid_t*)(Bw + boff[s]),
        (svoid_t*)(Bs + ldst[s]), 16, 0, 0);
  }
  __syncthreads();
  int cur = 0;
  for (int kt = 0; kt < 11; ++kt) {
    const int k1 = (kt + 1) * 32;
    const int nb = cur ^ 1;
#pragma unroll
    for (int s = 0; s < 2; ++s) {
      __builtin_amdgcn_global_load_lds((gvoid_t*)(A + aoff[s] + k1),
          (svoid_t*)(As + nb * 4096 + ldst[s]), 16, 0, 0);
      __builtin_amdgcn_global_load_lds((gvoid_t*)(Bw + boff[s] + k1),
          (svoid_t*)(Bs + nb * 4096 + ldst[s]), 16, 0, 0);
    }
    {
      const u16* Ab = As + cur * 4096;
      const u16* Bb = Bs + cur * 4096;
      bf16x8 af[4], bfr[4];
#pragma unroll
      for (int i = 0; i < 4; i++) af[i] = *(const bf16x8*)&Ab[abase + i * 512];
#pragma unroll
      for (int j = 0; j < 4; j++) bfr[j] = *(const bf16x8*)&Bb[bbase + j * 512];
#pragma unroll
      for (int i = 0; i < 4; i++)
#pragma unroll
        for (int j = 0; j < 4; j++)
          acc[i][j] = __builtin_amdgcn_mfma_f32_16x16x32_bf16(af[i], bfr[j], acc[i][j], 0, 0, 0);
    }
    __syncthreads();
    cur ^= 1;
  }
  {
    const u16* Ab = As + cur * 4096;
    const u16* Bb = Bs + cur * 4096;
    bf16x8 af[4], bfr[4];
#pragma unroll
    for (int i = 0; i < 4; i++) af[i] = *(const bf16x8*)&Ab[abase + i * 512];
#pragma unroll
    for (int j = 0; j < 4; j++) bfr[j] = *(const bf16x8*)&Bb[bbase + j * 512];
#pragma unroll
    for (int i = 0; i < 4; i++)
#pragma unroll
      for (int j = 0; j < 4; j++)
        acc[i][j] = __builtin_amdgcn_mfma_f32_16x16x32_bf16(af[i], bfr[j], acc[i][j], 0, 0, 0);
  }

  // epilogue (R1-exact): residual add + bias, fp32 out.
  // Batched per quadrant: issue all 16 x-loads, then all 16 add+stores.
  float bv[4];
#pragma unroll
  for (int j = 0; j < 4; j++) bv[j] = bias[n0 + wn + j * 16 + lm];
#pragma unroll
  for (int i = 0; i < 4; i++) {
    int rbase = m0 + wm + i * 16 + lk * 4;
    size_t orow[4];
#pragma unroll
    for (int r = 0; r < 4; r++) {
      int tok = rbase + r;
      int bt = tok / LM1;
      int l  = tok - bt * LM1;
      orow[r] = (size_t)(bt * LX + 1 + l) * CDIM + (n0 + wn + lm);
    }
    float xv[4][4];
#pragma unroll
    for (int r = 0; r < 4; r++)
#pragma unroll
      for (int j = 0; j < 4; j++)
        xv[r][j] = x[orow[r] + j * 16];
#pragma unroll
    for (int r = 0; r < 4; r++)
#pragma unroll
      for (int j = 0; j < 4; j++)
        out[orow[r] + j * 16] = xv[r][j] + acc[i][j][r] + bv[j];
  }
}

// ---------------- launch ----------------
extern "C" void kernel_launch(void* const* d_in, const int* in_sizes, int n_in,
                              void* d_out, int out_size, void* d_ws, size_t ws_size,
                              hipStream_t stream) {
  const float* x  = (const float*)d_in[0];
  const float* W1 = (const float*)d_in[1];
  const float* b1 = (const float*)d_in[2];
  const float* cw = (const float*)d_in[3];
  const float* cb = (const float*)d_in[4];
  const float* W2 = (const float*)d_in[5];
  const float* b2 = (const float*)d_in[6];
  float* out = (float*)d_out;

  // workspace: 78.3 MB total
  char* ws = (char*)d_ws;
  u16*   w1b = (u16*)(ws + 0);              //    589,824 B
  u16*   w2b = (u16*)(ws + 589824);         //    589,824 B
  float* cwT = (float*)(ws + 1179648);      //     41,472 B
  u16*   h1  = (u16*)(ws + 1245184);        // 38,535,168 B
  u16*   h2  = (u16*)(ws + 39780352);       // 38,535,168 B  (end 78,315,520)

  prep_small<<<1152, 256, 0, stream>>>((const float4*)x, (float4*)out,
                                       W1, W2, cw, w1b, w2b, cwT);
  fc1_gemm<<<MTOT / 128, 768, 0, stream>>>(x, w1b, b1, h1);
  dwconv  <<<dim3(BTOT, 12), 256, 0, stream>>>(h1, cwT, cb, h2);
  fc2_gemm<<<2352, 256, 0, stream>>>(h2, w2b, b2, x, out);
}